// Round 22
// baseline (2024.071 us; speedup 1.0000x reference)
//
#include <hip/hip_runtime.h>
#include <math.h>

// MetalWallQEQ: reciprocal-space Ewald QEQ for metal-wall charges.
// Round 22: retry abuild_g T14 pipeline with STATIC register indexing
// (template<int NLD>, full unroll -> rv[] stays in VGPRs; r20's failure was
// runtime-conditional rv -> scratch, rule #20). Math byte-identical to r21.
// NIT=112 kept (validated: absmax 0.0703, margin 1.43x).

#define NA 4096
#define NM 2048
#define METAL_Z 79
#define KH 7812          // (25^3-1)/2 half k-points
#define KHP 7936         // padded to 62*128 (pad entries have w=0)
#define NIT 112          // fixed CG iterations (graph-friendly)
#define NBLK_CG 64       // CG grid: 64 blocks x 1024 threads
#define CGT 1024
#define TWO_PI 6.283185307179586f

// ---- workspace byte offsets ----
#define OFF_CONSTS 0        // [0..8]=invT(cell) row-major, [9]=pref=4pi/V, [10]=J
#define OFF_SUMS   256      // scratch
#define OFF_FLAGS  512      // (legacy, zeroed)
#define OFF_KTAB   4096     // KHP * {gx,gy,gz,w} floats
#define OFF_FRAC   131072   // NA * {fx,fy,fz,0} fractional coords
#define OFF_MLIST  196608   // NM ints: metal position -> atom index
#define OFF_POSOF  204800   // NA ints: atom -> metal position (metal only)
#define OFF_SRW    221184   // KHP floats: w*Re S(k)
#define OFF_SIW    252928   // KHP floats: w*Im S(k)
#define OFF_BPART  284672   // 31*NM floats: field partials (from gbuild)
#define OFF_B      792576   // NA-NM ints: electrolyte atom list
#define OFF_VEC    800768   // x (2048), pad, r (at +4096)
#define OFF_WBUF   833536   // [parity][NM] u64 (w | tag<<32)  32KB
#define OFF_PBUF   866304   // [parity][3*64] u64 tagged partials  3KB
#define OFF_A      917504   // NM*NM floats (A + J on diagonal)
#define OFF_GHI    25165824u   // 2048*7936 uints (bf16 cos|sin hi)  ~65MB
#define OFF_GLO    90177536u   // 2048*7936 uints (bf16 cos|sin lo)  ~65MB

typedef short bf16x8 __attribute__((ext_vector_type(8)));
typedef float f32x4 __attribute__((ext_vector_type(4)));

__device__ __forceinline__ void sc_frac(float u, float& s, float& c) {
    float t = u - floorf(u);
    s = __builtin_amdgcn_sinf(t);
    c = __builtin_amdgcn_cosf(t);
}

__device__ __forceinline__ unsigned short bf16rne(float x) {
    unsigned u = __float_as_uint(x);
    unsigned r = u + 0x7fffu + ((u >> 16) & 1u);
    return (unsigned short)(r >> 16);
}

__device__ __forceinline__ unsigned long long pack_wt(float w, int tag) {
    return (unsigned long long)__float_as_uint(w) | ((unsigned long long)(unsigned)tag << 32);
}
__device__ __forceinline__ float lo_f(unsigned long long v) {
    return __uint_as_float((unsigned)v);
}

// -------- setup: cell inverse, frac coords, metal/electrolyte scans, zero tags --------
__global__ void k_setup(const float* __restrict__ pos, const float* __restrict__ cell,
                        const float* __restrict__ Jraw, const int* __restrict__ an,
                        float* __restrict__ wsf) {
    int tid = threadIdx.x;
    __shared__ float sM[9];
    __shared__ int sc[256];
    if (tid == 0) {
        float c00=cell[0],c01=cell[1],c02=cell[2];
        float c10=cell[3],c11=cell[4],c12=cell[5];
        float c20=cell[6],c21=cell[7],c22=cell[8];
        float det = c00*(c11*c22-c12*c21) - c01*(c10*c22-c12*c20) + c02*(c10*c21-c11*c20);
        float i00 =  (c11*c22 - c12*c21)/det;
        float i01 = -(c01*c22 - c02*c21)/det;
        float i02 =  (c01*c12 - c02*c11)/det;
        float i10 = -(c10*c22 - c12*c20)/det;
        float i11 =  (c00*c22 - c02*c20)/det;
        float i12 = -(c00*c12 - c02*c10)/det;
        float i20 =  (c10*c21 - c11*c20)/det;
        float i21 = -(c00*c21 - c01*c20)/det;
        float i22 =  (c00*c11 - c01*c10)/det;
        sM[0]=i00; sM[1]=i10; sM[2]=i20;
        sM[3]=i01; sM[4]=i11; sM[5]=i21;
        sM[6]=i02; sM[7]=i12; sM[8]=i22;
        float vol = fabsf(det);
        for (int m=0;m<9;m++) wsf[OFF_CONSTS/4 + m] = sM[m];
        wsf[OFF_CONSTS/4 + 9]  = 12.566370614359172f / vol;   // 4pi/V
        wsf[OFF_CONSTS/4 + 10] = Jraw[0]*Jraw[0];
    }
    __syncthreads();
    float M0=sM[0],M1=sM[1],M2=sM[2],M3=sM[3],M4=sM[4],M5=sM[5],M6=sM[6],M7=sM[7],M8=sM[8];
    for (int i=tid; i<NA; i+=256) {
        float x=pos[3*i], y=pos[3*i+1], z=pos[3*i+2];
        wsf[OFF_FRAC/4 + 4*i+0] = M0*x + M1*y + M2*z;
        wsf[OFF_FRAC/4 + 4*i+1] = M3*x + M4*y + M5*z;
        wsf[OFF_FRAC/4 + 4*i+2] = M6*x + M7*y + M8*z;
        wsf[OFF_FRAC/4 + 4*i+3] = 0.f;
    }
    ((int*)wsf)[OFF_FLAGS/4 + tid] = 0;
    if (tid < 4) wsf[OFF_SUMS/4 + tid] = 0.f;
    // zero CG sync tags: wbuf (4096 u64) + pbuf (384 u64), contiguous
    unsigned long long* tz = (unsigned long long*)((char*)wsf + OFF_WBUF);
    for (int i=tid; i<4480; i+=256) tz[i] = 0ull;
    // metal prefix scan (deterministic ordering == np.where order)
    int cnt = 0;
    int base_i = tid*16;
    for (int j=0;j<16;j++) cnt += (an[base_i+j]==METAL_Z) ? 1 : 0;
    sc[tid] = cnt; __syncthreads();
    for (int off=1; off<256; off<<=1) {
        int v = (tid>=off) ? sc[tid-off] : 0;
        __syncthreads();
        sc[tid] += v;
        __syncthreads();
    }
    int base = sc[tid] - cnt;          // metal exclusive prefix
    int ebase = base_i - base;         // electrolyte exclusive prefix
    int* mlist = (int*)wsf + OFF_MLIST/4;
    int* posof = (int*)wsf + OFF_POSOF/4;
    int* elist = (int*)wsf + OFF_B/4;
    for (int j=0;j<16;j++) {
        int i = base_i + j;
        if (an[i]==METAL_Z) { mlist[base] = i; posof[i] = base; base++; }
        else                { elist[ebase] = i; ebase++; }
    }
}

// -------- k-table: integer triple + weight w = 2*pref*exp(-k2/2)/k2 --------
__global__ void k_ktab(float* __restrict__ wsf) {
    int k = blockIdx.x*256 + threadIdx.x;
    if (k >= KHP) return;
    float4 out;
    if (k < KH) {
        int gx = k/625 - 12;
        int rem = k%625;
        int gy = rem/25 - 12;
        int gz = rem%25 - 12;
        const float* M = wsf + OFF_CONSTS/4;
        float pref = M[9];
        float kx = TWO_PI*(gx*M[0] + gy*M[3] + gz*M[6]);
        float ky = TWO_PI*(gx*M[1] + gy*M[4] + gz*M[7]);
        float kz = TWO_PI*(gx*M[2] + gy*M[5] + gz*M[8]);
        float k2 = kx*kx + ky*ky + kz*kz;
        float kfac = __expf(-0.5f*k2) / k2;
        out = make_float4((float)gx, (float)gy, (float)gz, 2.f*pref*kfac);
    } else {
        out = make_float4(0.f, 0.f, 0.f, 0.f);
    }
    *(float4*)(wsf + OFF_KTAB/4 + 4*k) = out;
}

// -------- structure factors over ELECTROLYTE atoms only (metal q = 0) --------
__global__ void k_srsi(const float* __restrict__ q, float* __restrict__ wsf) {
    int k = blockIdx.x;
    int tid = threadIdx.x;
    float4 kt = *(const float4*)(wsf + OFF_KTAB/4 + 4*k);
    const float* frac = wsf + OFF_FRAC/4;
    const int* elist = (const int*)wsf + OFF_B/4;
    float aR=0.f, aI=0.f;
    for (int ii=tid; ii<NA-NM; ii+=256) {
        int i = elist[ii];
        float qa = q[i];
        float4 f = *(const float4*)(frac + 4*i);
        float u = kt.x*f.x + kt.y*f.y + kt.z*f.z;
        float s,c; sc_frac(u, s, c);
        aR += qa*c; aI += qa*s;
    }
    __shared__ float sR[256], sI[256];
    sR[tid]=aR; sI[tid]=aI; __syncthreads();
    for (int off=128; off>0; off>>=1) {
        if (tid<off) { sR[tid]+=sR[tid+off]; sI[tid]+=sI[tid+off]; }
        __syncthreads();
    }
    if (tid==0) {
        wsf[OFF_SRW/4 + k] = kt.w * sR[0];
        wsf[OFF_SIW/4 + k] = kt.w * sI[0];
    }
}

// -------- G precompute + fused field partial --------
__global__ void k_gbuild(float* __restrict__ wsf, unsigned* __restrict__ ghi,
                         unsigned* __restrict__ glo) {
    int k = blockIdx.x*256 + threadIdx.x;   // 31*256 = 7936
    int m = blockIdx.y;                     // 2048
    int atom = ((const int*)wsf)[OFF_MLIST/4 + m];
    float4 f = *(const float4*)(wsf + OFF_FRAC/4 + 4*atom);
    float4 kt = *(const float4*)(wsf + OFF_KTAB/4 + 4*k);
    float rw = sqrtf(kt.w);
    float u = kt.x*f.x + kt.y*f.y + kt.z*f.z;
    float s, c; sc_frac(u, s, c);
    float part = fmaf(c, wsf[OFF_SRW/4 + k], s * wsf[OFF_SIW/4 + k]);
    float gc = rw*c, gs = rw*s;
    unsigned short hc = bf16rne(gc);
    float hcf = __uint_as_float(((unsigned)hc) << 16);
    unsigned short lc = bf16rne(gc - hcf);
    unsigned short hs = bf16rne(gs);
    float hsf = __uint_as_float(((unsigned)hs) << 16);
    unsigned short ls = bf16rne(gs - hsf);
    size_t off = (size_t)m*KHP + k;
    ghi[off] = (unsigned)hc | ((unsigned)hs << 16);
    glo[off] = (unsigned)lc | ((unsigned)ls << 16);
    __shared__ float sp[256];
    int tid = threadIdx.x;
    sp[tid] = part; __syncthreads();
    for (int o=128; o>0; o>>=1) {
        if (tid<o) sp[tid] += sp[tid+o];
        __syncthreads();
    }
    if (tid==0) wsf[OFF_BPART/4 + blockIdx.x*NM + m] = sp[0];
}

// -------- r0 = P*B = B - mean(B); B = -field (1 block x 1024) --------
__global__ void k_bfinal(float* __restrict__ wsf) {
    int tid = threadIdx.x;
    float b0 = 0.f, b1 = 0.f;
    for (int kc=0;kc<31;kc++) {
        b0 += wsf[OFF_BPART/4 + kc*NM + tid];
        b1 += wsf[OFF_BPART/4 + kc*NM + 1024 + tid];
    }
    b0 = -b0; b1 = -b1;
    __shared__ float sb[1024];
    sb[tid] = b0 + b1; __syncthreads();
    for (int off=512; off>0; off>>=1) {
        if (tid<off) sb[tid] += sb[tid+off];
        __syncthreads();
    }
    float mean = sb[0] * (1.f/NM);
    float* r = wsf + OFF_VEC/4 + 4096;
    r[tid]        = b0 - mean;
    r[1024 + tid] = b1 - mean;
}

// -------- pipelined Gram chunk loop: NLD compile-time -> rv in registers --------
template<int NLD>
__device__ __forceinline__ void gram_loop(
    unsigned* lb, const unsigned* gb0, int lrow8, int lane,
    const unsigned short* UHs, const unsigned short* ULs,
    const unsigned short* VHs, const unsigned short* VLs,
    int wr, int wc, int lr, int g4, f32x4 (&acc)[4][4])
{
    uint4 rv[NLD];
    #pragma unroll
    for (int i = 0; i < NLD; ++i)
        rv[i] = *(const uint4*)(gb0 + (size_t)(i*8 + lrow8)*KHP);
    const int NC = KHP/32;                     // 248 chunks
    for (int kc = 0; kc < NC; ++kc) {
        __syncthreads();                       // prior MFMA reads complete
        #pragma unroll
        for (int i = 0; i < NLD; ++i)
            *(uint4*)&lb[i*256 + lane*4] = rv[i];
        __syncthreads();                       // chunk staged
        if (kc+1 < NC) {                       // issue next chunk's loads now;
            const unsigned* gb = gb0 + (kc+1)*32;   // drain under the MFMAs
            #pragma unroll
            for (int i = 0; i < NLD; ++i)
                rv[i] = *(const uint4*)(gb + (size_t)(i*8 + lrow8)*KHP);
        }
        #pragma unroll
        for (int ks = 0; ks < 2; ++ks) {
            int cA = ks*4 + g4;
            bf16x8 ah[4], al[4], bh[4], bl[4];
            #pragma unroll
            for (int fi=0; fi<4; fi++) {
                int r = wr*64 + fi*16 + lr;
                int o = r*64 + ((cA ^ (r&7)) << 3);
                ah[fi] = *(const bf16x8*)&UHs[o];
                al[fi] = *(const bf16x8*)&ULs[o];
            }
            #pragma unroll
            for (int fj=0; fj<4; fj++) {
                int r = wc*64 + fj*16 + lr;
                int o = r*64 + ((cA ^ (r&7)) << 3);
                bh[fj] = *(const bf16x8*)&VHs[o];
                bl[fj] = *(const bf16x8*)&VLs[o];
            }
            #pragma unroll
            for (int fi=0; fi<4; fi++)
                #pragma unroll
                for (int fj=0; fj<4; fj++) {
                    acc[fi][fj] = __builtin_amdgcn_mfma_f32_16x16x32_bf16(ah[fi], bh[fj], acc[fi][fj], 0,0,0);
                    acc[fi][fj] = __builtin_amdgcn_mfma_f32_16x16x32_bf16(ah[fi], bl[fj], acc[fi][fj], 0,0,0);
                    acc[fi][fj] = __builtin_amdgcn_mfma_f32_16x16x32_bf16(al[fi], bh[fj], acc[fi][fj], 0,0,0);
                }
        }
    }
}

// -------- A build: 128x128 triangular Gram GEMM, pipelined (static NLD) --------
__launch_bounds__(256)
__global__ void k_abuild_g(float* __restrict__ wsf, const unsigned* __restrict__ ghi,
                           const unsigned* __restrict__ glo) {
    __shared__ unsigned Sh[16384];     // 64 KB
    int tid = threadIdx.x;
    int bid = blockIdx.x;
    int bi = (int)((sqrtf(8.f*bid + 1.f) - 1.f)*0.5f);
    while ((bi+1)*(bi+2)/2 <= bid) bi++;
    while (bi*(bi+1)/2 > bid) bi--;
    int bj = bid - bi*(bi+1)/2;
    bool diag = (bi == bj);
    float J = wsf[OFF_CONSTS/4 + 10];

    int w = tid >> 6, lane = tid & 63;
    int mat   = diag ? (w & 1) : w;
    int tb    = (diag ? bi : (w < 2 ? bi : bj)) * 128;
    int rbase = diag ? ((w >> 1) * 64) : 0;
    const unsigned* gsrc = (mat & 1) ? glo : ghi;
    int lrow8 = lane >> 3;
    int gcsw  = (lane & 7) ^ (lrow8 & 7);     // swizzled source chunk
    unsigned* lb = &Sh[mat*4096 + rbase*32];
    const unsigned* gb0 = gsrc + (size_t)(tb + rbase)*KHP + gcsw*4;

    int wr = w & 1, wc = w >> 1;
    int lr = lane & 15, g4 = lane >> 4;
    const unsigned short* UHs = (const unsigned short*)&Sh[0];
    const unsigned short* ULs = (const unsigned short*)&Sh[4096];
    const unsigned short* VHs = diag ? UHs : (const unsigned short*)&Sh[8192];
    const unsigned short* VLs = diag ? ULs : (const unsigned short*)&Sh[12288];

    f32x4 acc[4][4];
    #pragma unroll
    for (int i=0;i<4;i++)
        #pragma unroll
        for (int j=0;j<4;j++) acc[i][j] = (f32x4){0.f,0.f,0.f,0.f};

    if (diag) gram_loop<8> (lb, gb0, lrow8, lane, UHs, ULs, VHs, VLs, wr, wc, lr, g4, acc);
    else      gram_loop<16>(lb, gb0, lrow8, lane, UHs, ULs, VHs, VLs, wr, wc, lr, g4, acc);

    float* A = wsf + OFF_A/4;
    int rb4 = g4 * 4;
    #pragma unroll
    for (int fi=0; fi<4; fi++) {
        #pragma unroll
        for (int fj=0; fj<4; fj++) {
            int gj = bj*128 + wc*64 + fj*16 + lr;
            #pragma unroll
            for (int r=0; r<4; r++) {
                int gi = bi*128 + wr*64 + fi*16 + rb4 + r;
                float v = acc[fi][fj][r] + ((gi==gj)?J:0.f);
                A[(size_t)gi*NM + gj] = v;
                A[(size_t)gj*NM + gi] = v;
            }
        }
    }
}

// -------- persistent projected CG: 64x1024, data-carried (w,tag) sync --------
__launch_bounds__(CGT, 1)
__global__ void k_cg(float* __restrict__ wsf) {
    const float* A = wsf + OFF_A/4;
    float* vec = wsf + OFF_VEC/4;
    float* xg = vec;
    const float* rg = vec + 4096;
    unsigned long long* wbufg = (unsigned long long*)((char*)wsf + OFF_WBUF);
    unsigned long long* pbufg = (unsigned long long*)((char*)wsf + OFF_PBUF);

    __shared__ float rs[NM];
    __shared__ float wrow[32];
    __shared__ float red[4];

    int tid = threadIdx.x, bid = blockIdx.x;
    int rl = tid >> 5, lane = tid & 31;
    int row = bid*32 + rl;
    const float* Arow = A + (size_t)row*NM;
    int ca = 2*tid;

    ((float2*)rs)[tid] = ((const float2*)rg)[tid];
    __syncthreads();

    float s0=0.f, s1=0.f;
    float pr=0.f, xr=0.f;
    float gp=1.f, ap=1.f;

    for (int iter=0; iter<NIT; ++iter) {
        int t = iter + 1;
        unsigned long long* wb = wbufg + (iter&1)*2048;
        unsigned long long* pb = pbufg + (iter&1)*192;
        // ---- w_own = A_own * r, 32 lanes per row ----
        float acc=0.f;
        #pragma unroll 8
        for (int c=lane*4; c<NM; c+=128) {
            float4 a = *(const float4*)(Arow + c);
            float4 u = *(const float4*)(rs + c);
            acc += a.x*u.x + a.y*u.y + a.z*u.z + a.w*u.w;
        }
        #pragma unroll
        for (int off=1; off<32; off<<=1) acc += __shfl_xor(acc, off);
        if (lane == 0) {
            wrow[rl] = acc;
            __hip_atomic_store(&wb[row], pack_wt(acc, t),
                               __ATOMIC_RELAXED, __HIP_MEMORY_SCOPE_AGENT);
        }
        float rrow = (tid<32) ? rs[bid*32+tid] : 0.f;
        __syncthreads();   // (A) wrow visible for partials
        // ---- tagged block partials ----
        if (tid == 0) {
            float gb=0.f, db=0.f, mb=0.f;
            #pragma unroll
            for (int j=0;j<32;j++) {
                float rv = rs[bid*32+j];
                gb = fmaf(rv,rv,gb); db = fmaf(rv,wrow[j],db); mb += wrow[j];
            }
            __hip_atomic_store(&pb[bid],       pack_wt(gb, t), __ATOMIC_RELAXED, __HIP_MEMORY_SCOPE_AGENT);
            __hip_atomic_store(&pb[64+bid],    pack_wt(db, t), __ATOMIC_RELAXED, __HIP_MEMORY_SCOPE_AGENT);
            __hip_atomic_store(&pb[128+bid],   pack_wt(mb, t), __ATOMIC_RELAXED, __HIP_MEMORY_SCOPE_AGENT);
        }
        // ---- data-carried poll: each thread waits for ITS entries ----
        float w0, w1;
        if (tid < 64) {
            unsigned long long e0,e1,eg,ed,em;
            for (;;) {
                e0 = __hip_atomic_load(&wb[ca],     __ATOMIC_RELAXED, __HIP_MEMORY_SCOPE_AGENT);
                e1 = __hip_atomic_load(&wb[ca+1],   __ATOMIC_RELAXED, __HIP_MEMORY_SCOPE_AGENT);
                eg = __hip_atomic_load(&pb[tid],    __ATOMIC_RELAXED, __HIP_MEMORY_SCOPE_AGENT);
                ed = __hip_atomic_load(&pb[64+tid], __ATOMIC_RELAXED, __HIP_MEMORY_SCOPE_AGENT);
                em = __hip_atomic_load(&pb[128+tid],__ATOMIC_RELAXED, __HIP_MEMORY_SCOPE_AGENT);
                int ok = ((int)(e0>>32)==t) & ((int)(e1>>32)==t)
                       & ((int)(eg>>32)==t) & ((int)(ed>>32)==t) & ((int)(em>>32)==t);
                if (__all(ok)) break;
                __builtin_amdgcn_s_sleep(1);
            }
            w0 = lo_f(e0); w1 = lo_f(e1);
            float g = lo_f(eg), d = lo_f(ed), m = lo_f(em);
            #pragma unroll
            for (int off=1; off<64; off<<=1) {
                g += __shfl_xor(g,off); d += __shfl_xor(d,off); m += __shfl_xor(m,off);
            }
            if (tid==0) { red[0]=g; red[1]=d; red[2]=m; }
        } else {
            unsigned long long e0,e1;
            for (;;) {
                e0 = __hip_atomic_load(&wb[ca],   __ATOMIC_RELAXED, __HIP_MEMORY_SCOPE_AGENT);
                e1 = __hip_atomic_load(&wb[ca+1], __ATOMIC_RELAXED, __HIP_MEMORY_SCOPE_AGENT);
                int ok = ((int)(e0>>32)==t) & ((int)(e1>>32)==t);
                if (__all(ok)) break;
                __builtin_amdgcn_s_sleep(1);
            }
            w0 = lo_f(e0); w1 = lo_f(e1);
        }
        __syncthreads();   // (C) scalars ready
        float g = red[0], d = red[1];
        float m = red[2] * (1.f/NM);
        float b, a;
        if (iter == 0) { b=0.f; a=g/d; }
        else { b = g/gp; a = g/(d - b*g/ap); }
        gp=g; ap=a;
        if (tid < 32) {
            pr = (iter==0) ? rrow : fmaf(b, pr, rrow);
            xr = (iter==0) ? a*pr : fmaf(a, pr, xr);
        }
        float wt0 = w0 - m, wt1 = w1 - m;
        s0 = (iter==0) ? wt0 : fmaf(b, s0, wt0);
        s1 = (iter==0) ? wt1 : fmaf(b, s1, wt1);
        float2 rv2 = *(const float2*)(rs + ca);
        *(float2*)(rs + ca) = make_float2(fmaf(-a, s0, rv2.x), fmaf(-a, s1, rv2.y));
        __syncthreads();   // (D) rs consistent for next matvec
    }
    if (tid < 32) xg[bid*32+tid] = xr;
}

// -------- assemble output: metal -> x, electrolyte -> q --------
__global__ void k_out(const float* __restrict__ q, const int* __restrict__ an,
                      const float* __restrict__ wsf, float* __restrict__ out) {
    int i = blockIdx.x*256 + threadIdx.x;
    if (i >= NA) return;
    if (an[i]==METAL_Z) {
        int p = ((const int*)wsf)[OFF_POSOF/4 + i];
        out[i] = wsf[OFF_VEC/4 + p];
    } else {
        out[i] = q[i];
    }
}

extern "C" void kernel_launch(void* const* d_in, const int* in_sizes, int n_in,
                              void* d_out, int out_size, void* d_ws, size_t ws_size,
                              hipStream_t stream) {
    (void)in_sizes; (void)n_in; (void)out_size; (void)ws_size;
    const float* pos  = (const float*)d_in[0];
    const float* cell = (const float*)d_in[1];
    const float* q    = (const float*)d_in[2];
    const float* Jraw = (const float*)d_in[3];
    const int*   an   = (const int*)d_in[4];
    float* wsf = (float*)d_ws;
    float* out = (float*)d_out;
    unsigned* ghi = (unsigned*)((char*)d_ws + OFF_GHI);
    unsigned* glo = (unsigned*)((char*)d_ws + OFF_GLO);

    k_setup<<<1, 256, 0, stream>>>(pos, cell, Jraw, an, wsf);
    k_ktab<<<KHP/256, 256, 0, stream>>>(wsf);
    k_srsi<<<KHP, 256, 0, stream>>>(q, wsf);
    k_gbuild<<<dim3(31, 2048), 256, 0, stream>>>(wsf, ghi, glo);
    k_bfinal<<<1, 1024, 0, stream>>>(wsf);
    k_abuild_g<<<136, 256, 0, stream>>>(wsf, ghi, glo);
    k_cg<<<NBLK_CG, CGT, 0, stream>>>(wsf);
    k_out<<<NA/256, 256, 0, stream>>>(q, an, wsf, out);
}

// Round 23
// 1325.679 us; speedup vs baseline: 1.5268x; 1.5268x over previous
//
#include <hip/hip_runtime.h>
#include <math.h>

// MetalWallQEQ: reciprocal-space Ewald QEQ for metal-wall charges.
// Round 23: REVERT to r21 (best: 1326us). r22's templated static-index
// prefetch ALSO spilled (VGPR 108 + 103MB scratch writes: allocator refuses
// 64 live VGPRs across barrier+MFMA region) -> pipeline idea abandoned.
// Final config: G-precompute + fused field, elist-srsi, MFMA split-bf16
// Gram GEMM, data-carried tag-sync projected CG (64x1024), NIT=112.

#define NA 4096
#define NM 2048
#define METAL_Z 79
#define KH 7812          // (25^3-1)/2 half k-points
#define KHP 7936         // padded to 62*128 (pad entries have w=0)
#define NIT 112          // fixed CG iterations (graph-friendly)
#define NBLK_CG 64       // CG grid: 64 blocks x 1024 threads
#define CGT 1024
#define TWO_PI 6.283185307179586f

// ---- workspace byte offsets ----
#define OFF_CONSTS 0        // [0..8]=invT(cell) row-major, [9]=pref=4pi/V, [10]=J
#define OFF_SUMS   256      // scratch
#define OFF_FLAGS  512      // (legacy, zeroed)
#define OFF_KTAB   4096     // KHP * {gx,gy,gz,w} floats
#define OFF_FRAC   131072   // NA * {fx,fy,fz,0} fractional coords
#define OFF_MLIST  196608   // NM ints: metal position -> atom index
#define OFF_POSOF  204800   // NA ints: atom -> metal position (metal only)
#define OFF_SRW    221184   // KHP floats: w*Re S(k)
#define OFF_SIW    252928   // KHP floats: w*Im S(k)
#define OFF_BPART  284672   // 31*NM floats: field partials (from gbuild)
#define OFF_B      792576   // NA-NM ints: electrolyte atom list
#define OFF_VEC    800768   // x (2048), pad, r (at +4096)
#define OFF_WBUF   833536   // [parity][NM] u64 (w | tag<<32)  32KB
#define OFF_PBUF   866304   // [parity][3*64] u64 tagged partials  3KB
#define OFF_A      917504   // NM*NM floats (A + J on diagonal)
#define OFF_GHI    25165824u   // 2048*7936 uints (bf16 cos|sin hi)  ~65MB
#define OFF_GLO    90177536u   // 2048*7936 uints (bf16 cos|sin lo)  ~65MB

typedef short bf16x8 __attribute__((ext_vector_type(8)));
typedef float f32x4 __attribute__((ext_vector_type(4)));

__device__ __forceinline__ void sc_frac(float u, float& s, float& c) {
    float t = u - floorf(u);
    s = __builtin_amdgcn_sinf(t);
    c = __builtin_amdgcn_cosf(t);
}

__device__ __forceinline__ unsigned short bf16rne(float x) {
    unsigned u = __float_as_uint(x);
    unsigned r = u + 0x7fffu + ((u >> 16) & 1u);
    return (unsigned short)(r >> 16);
}

__device__ __forceinline__ unsigned long long pack_wt(float w, int tag) {
    return (unsigned long long)__float_as_uint(w) | ((unsigned long long)(unsigned)tag << 32);
}
__device__ __forceinline__ float lo_f(unsigned long long v) {
    return __uint_as_float((unsigned)v);
}

// -------- setup: cell inverse, frac coords, metal/electrolyte scans, zero tags --------
__global__ void k_setup(const float* __restrict__ pos, const float* __restrict__ cell,
                        const float* __restrict__ Jraw, const int* __restrict__ an,
                        float* __restrict__ wsf) {
    int tid = threadIdx.x;
    __shared__ float sM[9];
    __shared__ int sc[256];
    if (tid == 0) {
        float c00=cell[0],c01=cell[1],c02=cell[2];
        float c10=cell[3],c11=cell[4],c12=cell[5];
        float c20=cell[6],c21=cell[7],c22=cell[8];
        float det = c00*(c11*c22-c12*c21) - c01*(c10*c22-c12*c20) + c02*(c10*c21-c11*c20);
        float i00 =  (c11*c22 - c12*c21)/det;
        float i01 = -(c01*c22 - c02*c21)/det;
        float i02 =  (c01*c12 - c02*c11)/det;
        float i10 = -(c10*c22 - c12*c20)/det;
        float i11 =  (c00*c22 - c02*c20)/det;
        float i12 = -(c00*c12 - c02*c10)/det;
        float i20 =  (c10*c21 - c11*c20)/det;
        float i21 = -(c00*c21 - c01*c20)/det;
        float i22 =  (c00*c11 - c01*c10)/det;
        sM[0]=i00; sM[1]=i10; sM[2]=i20;
        sM[3]=i01; sM[4]=i11; sM[5]=i21;
        sM[6]=i02; sM[7]=i12; sM[8]=i22;
        float vol = fabsf(det);
        for (int m=0;m<9;m++) wsf[OFF_CONSTS/4 + m] = sM[m];
        wsf[OFF_CONSTS/4 + 9]  = 12.566370614359172f / vol;   // 4pi/V
        wsf[OFF_CONSTS/4 + 10] = Jraw[0]*Jraw[0];
    }
    __syncthreads();
    float M0=sM[0],M1=sM[1],M2=sM[2],M3=sM[3],M4=sM[4],M5=sM[5],M6=sM[6],M7=sM[7],M8=sM[8];
    for (int i=tid; i<NA; i+=256) {
        float x=pos[3*i], y=pos[3*i+1], z=pos[3*i+2];
        wsf[OFF_FRAC/4 + 4*i+0] = M0*x + M1*y + M2*z;
        wsf[OFF_FRAC/4 + 4*i+1] = M3*x + M4*y + M5*z;
        wsf[OFF_FRAC/4 + 4*i+2] = M6*x + M7*y + M8*z;
        wsf[OFF_FRAC/4 + 4*i+3] = 0.f;
    }
    ((int*)wsf)[OFF_FLAGS/4 + tid] = 0;
    if (tid < 4) wsf[OFF_SUMS/4 + tid] = 0.f;
    // zero CG sync tags: wbuf (4096 u64) + pbuf (384 u64), contiguous
    unsigned long long* tz = (unsigned long long*)((char*)wsf + OFF_WBUF);
    for (int i=tid; i<4480; i+=256) tz[i] = 0ull;
    // metal prefix scan (deterministic ordering == np.where order)
    int cnt = 0;
    int base_i = tid*16;
    for (int j=0;j<16;j++) cnt += (an[base_i+j]==METAL_Z) ? 1 : 0;
    sc[tid] = cnt; __syncthreads();
    for (int off=1; off<256; off<<=1) {
        int v = (tid>=off) ? sc[tid-off] : 0;
        __syncthreads();
        sc[tid] += v;
        __syncthreads();
    }
    int base = sc[tid] - cnt;          // metal exclusive prefix
    int ebase = base_i - base;         // electrolyte exclusive prefix
    int* mlist = (int*)wsf + OFF_MLIST/4;
    int* posof = (int*)wsf + OFF_POSOF/4;
    int* elist = (int*)wsf + OFF_B/4;
    for (int j=0;j<16;j++) {
        int i = base_i + j;
        if (an[i]==METAL_Z) { mlist[base] = i; posof[i] = base; base++; }
        else                { elist[ebase] = i; ebase++; }
    }
}

// -------- k-table: integer triple + weight w = 2*pref*exp(-k2/2)/k2 --------
__global__ void k_ktab(float* __restrict__ wsf) {
    int k = blockIdx.x*256 + threadIdx.x;
    if (k >= KHP) return;
    float4 out;
    if (k < KH) {
        int gx = k/625 - 12;
        int rem = k%625;
        int gy = rem/25 - 12;
        int gz = rem%25 - 12;
        const float* M = wsf + OFF_CONSTS/4;
        float pref = M[9];
        float kx = TWO_PI*(gx*M[0] + gy*M[3] + gz*M[6]);
        float ky = TWO_PI*(gx*M[1] + gy*M[4] + gz*M[7]);
        float kz = TWO_PI*(gx*M[2] + gy*M[5] + gz*M[8]);
        float k2 = kx*kx + ky*ky + kz*kz;
        float kfac = __expf(-0.5f*k2) / k2;
        out = make_float4((float)gx, (float)gy, (float)gz, 2.f*pref*kfac);
    } else {
        out = make_float4(0.f, 0.f, 0.f, 0.f);
    }
    *(float4*)(wsf + OFF_KTAB/4 + 4*k) = out;
}

// -------- structure factors over ELECTROLYTE atoms only (metal q = 0) --------
__global__ void k_srsi(const float* __restrict__ q, float* __restrict__ wsf) {
    int k = blockIdx.x;
    int tid = threadIdx.x;
    float4 kt = *(const float4*)(wsf + OFF_KTAB/4 + 4*k);
    const float* frac = wsf + OFF_FRAC/4;
    const int* elist = (const int*)wsf + OFF_B/4;
    float aR=0.f, aI=0.f;
    for (int ii=tid; ii<NA-NM; ii+=256) {
        int i = elist[ii];
        float qa = q[i];
        float4 f = *(const float4*)(frac + 4*i);
        float u = kt.x*f.x + kt.y*f.y + kt.z*f.z;
        float s,c; sc_frac(u, s, c);
        aR += qa*c; aI += qa*s;
    }
    __shared__ float sR[256], sI[256];
    sR[tid]=aR; sI[tid]=aI; __syncthreads();
    for (int off=128; off>0; off>>=1) {
        if (tid<off) { sR[tid]+=sR[tid+off]; sI[tid]+=sI[tid+off]; }
        __syncthreads();
    }
    if (tid==0) {
        wsf[OFF_SRW/4 + k] = kt.w * sR[0];
        wsf[OFF_SIW/4 + k] = kt.w * sI[0];
    }
}

// -------- G precompute + fused field partial --------
__global__ void k_gbuild(float* __restrict__ wsf, unsigned* __restrict__ ghi,
                         unsigned* __restrict__ glo) {
    int k = blockIdx.x*256 + threadIdx.x;   // 31*256 = 7936
    int m = blockIdx.y;                     // 2048
    int atom = ((const int*)wsf)[OFF_MLIST/4 + m];
    float4 f = *(const float4*)(wsf + OFF_FRAC/4 + 4*atom);
    float4 kt = *(const float4*)(wsf + OFF_KTAB/4 + 4*k);
    float rw = sqrtf(kt.w);
    float u = kt.x*f.x + kt.y*f.y + kt.z*f.z;
    float s, c; sc_frac(u, s, c);
    float part = fmaf(c, wsf[OFF_SRW/4 + k], s * wsf[OFF_SIW/4 + k]);
    float gc = rw*c, gs = rw*s;
    unsigned short hc = bf16rne(gc);
    float hcf = __uint_as_float(((unsigned)hc) << 16);
    unsigned short lc = bf16rne(gc - hcf);
    unsigned short hs = bf16rne(gs);
    float hsf = __uint_as_float(((unsigned)hs) << 16);
    unsigned short ls = bf16rne(gs - hsf);
    size_t off = (size_t)m*KHP + k;
    ghi[off] = (unsigned)hc | ((unsigned)hs << 16);
    glo[off] = (unsigned)lc | ((unsigned)ls << 16);
    __shared__ float sp[256];
    int tid = threadIdx.x;
    sp[tid] = part; __syncthreads();
    for (int o=128; o>0; o>>=1) {
        if (tid<o) sp[tid] += sp[tid+o];
        __syncthreads();
    }
    if (tid==0) wsf[OFF_BPART/4 + blockIdx.x*NM + m] = sp[0];
}

// -------- r0 = P*B = B - mean(B); B = -field (1 block x 1024) --------
__global__ void k_bfinal(float* __restrict__ wsf) {
    int tid = threadIdx.x;
    float b0 = 0.f, b1 = 0.f;
    for (int kc=0;kc<31;kc++) {
        b0 += wsf[OFF_BPART/4 + kc*NM + tid];
        b1 += wsf[OFF_BPART/4 + kc*NM + 1024 + tid];
    }
    b0 = -b0; b1 = -b1;
    __shared__ float sb[1024];
    sb[tid] = b0 + b1; __syncthreads();
    for (int off=512; off>0; off>>=1) {
        if (tid<off) sb[tid] += sb[tid+off];
        __syncthreads();
    }
    float mean = sb[0] * (1.f/NM);
    float* r = wsf + OFF_VEC/4 + 4096;
    r[tid]        = b0 - mean;
    r[1024 + tid] = b1 - mean;
}

// -------- A build: 128x128 triangular Gram GEMM from precomputed G (r19/r21) --------
__launch_bounds__(256)
__global__ void k_abuild_g(float* __restrict__ wsf, const unsigned* __restrict__ ghi,
                           const unsigned* __restrict__ glo) {
    __shared__ unsigned Sh[16384];     // 64 KB
    int tid = threadIdx.x;
    int bid = blockIdx.x;
    int bi = (int)((sqrtf(8.f*bid + 1.f) - 1.f)*0.5f);
    while ((bi+1)*(bi+2)/2 <= bid) bi++;
    while (bi*(bi+1)/2 > bid) bi--;
    int bj = bid - bi*(bi+1)/2;
    bool diag = (bi == bj);
    float J = wsf[OFF_CONSTS/4 + 10];

    int w = tid >> 6, lane = tid & 63;
    int mat   = diag ? (w & 1) : w;
    int tb    = (diag ? bi : (w < 2 ? bi : bj)) * 128;
    int rbase = diag ? ((w >> 1) * 64) : 0;
    int nld   = diag ? 8 : 16;
    const unsigned* gsrc = (mat & 1) ? glo : ghi;
    int lrow8 = lane >> 3;
    int gcsw  = (lane & 7) ^ (lrow8 & 7);     // swizzled source chunk
    unsigned* lb = &Sh[mat*4096 + rbase*32];
    const unsigned* gb0 = gsrc + (size_t)(tb + rbase)*KHP + gcsw*4;

    int wr = w & 1, wc = w >> 1;
    int lr = lane & 15, g4 = lane >> 4;
    const unsigned short* UHs = (const unsigned short*)&Sh[0];
    const unsigned short* ULs = (const unsigned short*)&Sh[4096];
    const unsigned short* VHs = diag ? UHs : (const unsigned short*)&Sh[8192];
    const unsigned short* VLs = diag ? ULs : (const unsigned short*)&Sh[12288];

    f32x4 acc[4][4];
    #pragma unroll
    for (int i=0;i<4;i++)
        #pragma unroll
        for (int j=0;j<4;j++) acc[i][j] = (f32x4){0.f,0.f,0.f,0.f};

    for (int kc = 0; kc < KHP/32; ++kc) {
        __syncthreads();
        const unsigned* gb = gb0 + kc*32;
        #pragma unroll
        for (int i = 0; i < 16; ++i) {
            if (i < nld) {
                uint4 v = *(const uint4*)(gb + (size_t)(i*8 + lrow8)*KHP);
                *(uint4*)&lb[i*256 + lane*4] = v;
            }
        }
        __syncthreads();
        #pragma unroll
        for (int ks = 0; ks < 2; ++ks) {
            int cA = ks*4 + g4;
            bf16x8 ah[4], al[4], bh[4], bl[4];
            #pragma unroll
            for (int fi=0; fi<4; fi++) {
                int r = wr*64 + fi*16 + lr;
                int o = r*64 + ((cA ^ (r&7)) << 3);
                ah[fi] = *(const bf16x8*)&UHs[o];
                al[fi] = *(const bf16x8*)&ULs[o];
            }
            #pragma unroll
            for (int fj=0; fj<4; fj++) {
                int r = wc*64 + fj*16 + lr;
                int o = r*64 + ((cA ^ (r&7)) << 3);
                bh[fj] = *(const bf16x8*)&VHs[o];
                bl[fj] = *(const bf16x8*)&VLs[o];
            }
            #pragma unroll
            for (int fi=0; fi<4; fi++)
                #pragma unroll
                for (int fj=0; fj<4; fj++) {
                    acc[fi][fj] = __builtin_amdgcn_mfma_f32_16x16x32_bf16(ah[fi], bh[fj], acc[fi][fj], 0,0,0);
                    acc[fi][fj] = __builtin_amdgcn_mfma_f32_16x16x32_bf16(ah[fi], bl[fj], acc[fi][fj], 0,0,0);
                    acc[fi][fj] = __builtin_amdgcn_mfma_f32_16x16x32_bf16(al[fi], bh[fj], acc[fi][fj], 0,0,0);
                }
        }
    }

    float* A = wsf + OFF_A/4;
    int rb4 = g4 * 4;
    #pragma unroll
    for (int fi=0; fi<4; fi++) {
        #pragma unroll
        for (int fj=0; fj<4; fj++) {
            int gj = bj*128 + wc*64 + fj*16 + lr;
            #pragma unroll
            for (int r=0; r<4; r++) {
                int gi = bi*128 + wr*64 + fi*16 + rb4 + r;
                float v = acc[fi][fj][r] + ((gi==gj)?J:0.f);
                A[(size_t)gi*NM + gj] = v;
                A[(size_t)gj*NM + gi] = v;
            }
        }
    }
}

// -------- persistent projected CG: 64x1024, data-carried (w,tag) sync --------
__launch_bounds__(CGT, 1)
__global__ void k_cg(float* __restrict__ wsf) {
    const float* A = wsf + OFF_A/4;
    float* vec = wsf + OFF_VEC/4;
    float* xg = vec;
    const float* rg = vec + 4096;
    unsigned long long* wbufg = (unsigned long long*)((char*)wsf + OFF_WBUF);
    unsigned long long* pbufg = (unsigned long long*)((char*)wsf + OFF_PBUF);

    __shared__ float rs[NM];
    __shared__ float wrow[32];
    __shared__ float red[4];

    int tid = threadIdx.x, bid = blockIdx.x;
    int rl = tid >> 5, lane = tid & 31;
    int row = bid*32 + rl;
    const float* Arow = A + (size_t)row*NM;
    int ca = 2*tid;

    ((float2*)rs)[tid] = ((const float2*)rg)[tid];
    __syncthreads();

    float s0=0.f, s1=0.f;
    float pr=0.f, xr=0.f;
    float gp=1.f, ap=1.f;

    for (int iter=0; iter<NIT; ++iter) {
        int t = iter + 1;
        unsigned long long* wb = wbufg + (iter&1)*2048;
        unsigned long long* pb = pbufg + (iter&1)*192;
        // ---- w_own = A_own * r, 32 lanes per row ----
        float acc=0.f;
        #pragma unroll 8
        for (int c=lane*4; c<NM; c+=128) {
            float4 a = *(const float4*)(Arow + c);
            float4 u = *(const float4*)(rs + c);
            acc += a.x*u.x + a.y*u.y + a.z*u.z + a.w*u.w;
        }
        #pragma unroll
        for (int off=1; off<32; off<<=1) acc += __shfl_xor(acc, off);
        if (lane == 0) {
            wrow[rl] = acc;
            __hip_atomic_store(&wb[row], pack_wt(acc, t),
                               __ATOMIC_RELAXED, __HIP_MEMORY_SCOPE_AGENT);
        }
        float rrow = (tid<32) ? rs[bid*32+tid] : 0.f;
        __syncthreads();   // (A) wrow visible for partials
        // ---- tagged block partials ----
        if (tid == 0) {
            float gb=0.f, db=0.f, mb=0.f;
            #pragma unroll
            for (int j=0;j<32;j++) {
                float rv = rs[bid*32+j];
                gb = fmaf(rv,rv,gb); db = fmaf(rv,wrow[j],db); mb += wrow[j];
            }
            __hip_atomic_store(&pb[bid],       pack_wt(gb, t), __ATOMIC_RELAXED, __HIP_MEMORY_SCOPE_AGENT);
            __hip_atomic_store(&pb[64+bid],    pack_wt(db, t), __ATOMIC_RELAXED, __HIP_MEMORY_SCOPE_AGENT);
            __hip_atomic_store(&pb[128+bid],   pack_wt(mb, t), __ATOMIC_RELAXED, __HIP_MEMORY_SCOPE_AGENT);
        }
        // ---- data-carried poll: each thread waits for ITS entries ----
        float w0, w1;
        if (tid < 64) {
            unsigned long long e0,e1,eg,ed,em;
            for (;;) {
                e0 = __hip_atomic_load(&wb[ca],     __ATOMIC_RELAXED, __HIP_MEMORY_SCOPE_AGENT);
                e1 = __hip_atomic_load(&wb[ca+1],   __ATOMIC_RELAXED, __HIP_MEMORY_SCOPE_AGENT);
                eg = __hip_atomic_load(&pb[tid],    __ATOMIC_RELAXED, __HIP_MEMORY_SCOPE_AGENT);
                ed = __hip_atomic_load(&pb[64+tid], __ATOMIC_RELAXED, __HIP_MEMORY_SCOPE_AGENT);
                em = __hip_atomic_load(&pb[128+tid],__ATOMIC_RELAXED, __HIP_MEMORY_SCOPE_AGENT);
                int ok = ((int)(e0>>32)==t) & ((int)(e1>>32)==t)
                       & ((int)(eg>>32)==t) & ((int)(ed>>32)==t) & ((int)(em>>32)==t);
                if (__all(ok)) break;
                __builtin_amdgcn_s_sleep(1);
            }
            w0 = lo_f(e0); w1 = lo_f(e1);
            float g = lo_f(eg), d = lo_f(ed), m = lo_f(em);
            #pragma unroll
            for (int off=1; off<64; off<<=1) {
                g += __shfl_xor(g,off); d += __shfl_xor(d,off); m += __shfl_xor(m,off);
            }
            if (tid==0) { red[0]=g; red[1]=d; red[2]=m; }
        } else {
            unsigned long long e0,e1;
            for (;;) {
                e0 = __hip_atomic_load(&wb[ca],   __ATOMIC_RELAXED, __HIP_MEMORY_SCOPE_AGENT);
                e1 = __hip_atomic_load(&wb[ca+1], __ATOMIC_RELAXED, __HIP_MEMORY_SCOPE_AGENT);
                int ok = ((int)(e0>>32)==t) & ((int)(e1>>32)==t);
                if (__all(ok)) break;
                __builtin_amdgcn_s_sleep(1);
            }
            w0 = lo_f(e0); w1 = lo_f(e1);
        }
        __syncthreads();   // (C) scalars ready
        float g = red[0], d = red[1];
        float m = red[2] * (1.f/NM);
        float b, a;
        if (iter == 0) { b=0.f; a=g/d; }
        else { b = g/gp; a = g/(d - b*g/ap); }
        gp=g; ap=a;
        if (tid < 32) {
            pr = (iter==0) ? rrow : fmaf(b, pr, rrow);
            xr = (iter==0) ? a*pr : fmaf(a, pr, xr);
        }
        float wt0 = w0 - m, wt1 = w1 - m;
        s0 = (iter==0) ? wt0 : fmaf(b, s0, wt0);
        s1 = (iter==0) ? wt1 : fmaf(b, s1, wt1);
        float2 rv2 = *(const float2*)(rs + ca);
        *(float2*)(rs + ca) = make_float2(fmaf(-a, s0, rv2.x), fmaf(-a, s1, rv2.y));
        __syncthreads();   // (D) rs consistent for next matvec
    }
    if (tid < 32) xg[bid*32+tid] = xr;
}

// -------- assemble output: metal -> x, electrolyte -> q --------
__global__ void k_out(const float* __restrict__ q, const int* __restrict__ an,
                      const float* __restrict__ wsf, float* __restrict__ out) {
    int i = blockIdx.x*256 + threadIdx.x;
    if (i >= NA) return;
    if (an[i]==METAL_Z) {
        int p = ((const int*)wsf)[OFF_POSOF/4 + i];
        out[i] = wsf[OFF_VEC/4 + p];
    } else {
        out[i] = q[i];
    }
}

extern "C" void kernel_launch(void* const* d_in, const int* in_sizes, int n_in,
                              void* d_out, int out_size, void* d_ws, size_t ws_size,
                              hipStream_t stream) {
    (void)in_sizes; (void)n_in; (void)out_size; (void)ws_size;
    const float* pos  = (const float*)d_in[0];
    const float* cell = (const float*)d_in[1];
    const float* q    = (const float*)d_in[2];
    const float* Jraw = (const float*)d_in[3];
    const int*   an   = (const int*)d_in[4];
    float* wsf = (float*)d_ws;
    float* out = (float*)d_out;
    unsigned* ghi = (unsigned*)((char*)d_ws + OFF_GHI);
    unsigned* glo = (unsigned*)((char*)d_ws + OFF_GLO);

    k_setup<<<1, 256, 0, stream>>>(pos, cell, Jraw, an, wsf);
    k_ktab<<<KHP/256, 256, 0, stream>>>(wsf);
    k_srsi<<<KHP, 256, 0, stream>>>(q, wsf);
    k_gbuild<<<dim3(31, 2048), 256, 0, stream>>>(wsf, ghi, glo);
    k_bfinal<<<1, 1024, 0, stream>>>(wsf);
    k_abuild_g<<<136, 256, 0, stream>>>(wsf, ghi, glo);
    k_cg<<<NBLK_CG, CGT, 0, stream>>>(wsf);
    k_out<<<NA/256, 256, 0, stream>>>(q, an, wsf, out);
}